// Round 1
// baseline (1090.912 us; speedup 1.0000x reference)
//
#include <hip/hip_runtime.h>
#include <hip/hip_bf16.h>

#define BQ 8
#define SS 1024
#define DD 256
#define HH 8
#define DKK 32
#define HIDD 1024

// ---------------- LayerNorm: one row (D=256) per block of 256 threads ----------------
__global__ __launch_bounds__(256) void ln_kernel(const float* __restrict__ in,
    const float* __restrict__ gamma, const float* __restrict__ beta,
    float* __restrict__ out)
{
    const int row = blockIdx.x;
    const int t = threadIdx.x;
    const float v = in[(long)row * DD + t];
    float s = v, s2 = v * v;
#pragma unroll
    for (int off = 1; off < 64; off <<= 1) {
        s += __shfl_xor(s, off);
        s2 += __shfl_xor(s2, off);
    }
    __shared__ float w1[4], w2[4];
    if ((t & 63) == 0) { w1[t >> 6] = s; w2[t >> 6] = s2; }
    __syncthreads();
    s = w1[0] + w1[1] + w1[2] + w1[3];
    s2 = w2[0] + w2[1] + w2[2] + w2[3];
    const float mean = s * (1.f / DD);
    const float var = s2 * (1.f / DD) - mean * mean;
    const float rs = rsqrtf(var + 1e-5f);
    out[(long)row * DD + t] = (v - mean) * rs * gamma[t] + beta[t];
}

// ---------------- Generic tiled fp32 GEMM: C = op(A)@B (+bias) (+Res) (relu) --------
// 64x64 tile, BK=16, 256 threads, 4x4 per thread. All dims divide tiles exactly.
template<bool TRANS_A, bool RELU>
__global__ __launch_bounds__(256) void gemm_kernel(
    const float* __restrict__ A, const float* __restrict__ B,
    const float* __restrict__ bias, const float* __restrict__ Res,
    float* __restrict__ C, int M, int N, int K,
    int lda, int ldb, int ldc, int ldres,
    long bsA, long bsB, long bsC, long bsRes)
{
    const int zb = blockIdx.z;
    A += bsA * zb; B += bsB * zb; C += bsC * zb;
    const float* Rp = Res ? Res + bsRes * zb : nullptr;
    const int n0 = blockIdx.x * 64;
    const int m0 = blockIdx.y * 64;
    const int tid = threadIdx.x;
    const int tx = tid & 15;
    const int ty = tid >> 4;
    __shared__ float As[16][68];
    __shared__ float Bs[16][68];
    float acc[4][4] = {};
    for (int k0 = 0; k0 < K; k0 += 16) {
        if (!TRANS_A) {
            const int am = tid >> 2;           // 0..63
            const int ak = (tid & 3) << 2;     // 0,4,8,12
            const float4 a4 = *(const float4*)(A + (long)(m0 + am) * lda + k0 + ak);
            As[ak + 0][am] = a4.x; As[ak + 1][am] = a4.y;
            As[ak + 2][am] = a4.z; As[ak + 3][am] = a4.w;
        } else {
            const int ak = tid >> 4;           // 0..15
            const int am = (tid & 15) << 2;    // 0..60
            const float4 a4 = *(const float4*)(A + (long)(k0 + ak) * lda + m0 + am);
            As[ak][am + 0] = a4.x; As[ak][am + 1] = a4.y;
            As[ak][am + 2] = a4.z; As[ak][am + 3] = a4.w;
        }
        {
            const int bk = tid >> 4;           // 0..15
            const int bn = (tid & 15) << 2;    // 0..60
            const float4 b4 = *(const float4*)(B + (long)(k0 + bk) * ldb + n0 + bn);
            Bs[bk][bn + 0] = b4.x; Bs[bk][bn + 1] = b4.y;
            Bs[bk][bn + 2] = b4.z; Bs[bk][bn + 3] = b4.w;
        }
        __syncthreads();
#pragma unroll
        for (int kk = 0; kk < 16; kk++) {
            float a[4], bb[4];
#pragma unroll
            for (int i = 0; i < 4; i++) a[i] = As[kk][ty * 4 + i];
#pragma unroll
            for (int j = 0; j < 4; j++) bb[j] = Bs[kk][tx * 4 + j];
#pragma unroll
            for (int i = 0; i < 4; i++)
#pragma unroll
                for (int j = 0; j < 4; j++)
                    acc[i][j] += a[i] * bb[j];
        }
        __syncthreads();
    }
    float bv[4] = {0.f, 0.f, 0.f, 0.f};
    if (bias) {
#pragma unroll
        for (int j = 0; j < 4; j++) bv[j] = bias[n0 + tx * 4 + j];
    }
#pragma unroll
    for (int i = 0; i < 4; i++) {
        const int m = m0 + ty * 4 + i;
        float vals[4];
#pragma unroll
        for (int j = 0; j < 4; j++) vals[j] = acc[i][j] + bv[j];
        if (Rp) {
            const float4 r4 = *(const float4*)(Rp + (long)m * ldres + n0 + tx * 4);
            vals[0] += r4.x; vals[1] += r4.y; vals[2] += r4.z; vals[3] += r4.w;
        }
        if (RELU) {
#pragma unroll
            for (int j = 0; j < 4; j++) vals[j] = fmaxf(vals[j], 0.f);
        }
        float4 o4; o4.x = vals[0]; o4.y = vals[1]; o4.z = vals[2]; o4.w = vals[3];
        *(float4*)(C + (long)m * ldc + n0 + tx * 4) = o4;
    }
}

// ---------------- Pack rel_pos: packed[b,q,k] = rp[b,q,k] + 10*rp[b,k,q] (uint8) ----
__global__ __launch_bounds__(256) void pack_kernel(const int* __restrict__ rp,
    unsigned char* __restrict__ packed)
{
    const int kt = blockIdx.x, qt = blockIdx.y, b = blockIdx.z;
    __shared__ int tA[32][33];
    __shared__ int tB[32][33];
    const int tid = threadIdx.x;
    const int i = tid >> 3;            // 0..31
    const int j0 = (tid & 7) << 2;     // 0..28
    const long base = (long)b * SS * SS;
    const int4 a4 = *(const int4*)(rp + base + (long)(qt * 32 + i) * SS + kt * 32 + j0);
    tA[i][j0 + 0] = a4.x; tA[i][j0 + 1] = a4.y; tA[i][j0 + 2] = a4.z; tA[i][j0 + 3] = a4.w;
    const int4 b4 = *(const int4*)(rp + base + (long)(kt * 32 + i) * SS + qt * 32 + j0);
    tB[i][j0 + 0] = b4.x; tB[i][j0 + 1] = b4.y; tB[i][j0 + 2] = b4.z; tB[i][j0 + 3] = b4.w;
    __syncthreads();
    uchar4 o4;
    o4.x = (unsigned char)(tA[i][j0 + 0] + 10 * tB[j0 + 0][i]);
    o4.y = (unsigned char)(tA[i][j0 + 1] + 10 * tB[j0 + 1][i]);
    o4.z = (unsigned char)(tA[i][j0 + 2] + 10 * tB[j0 + 2][i]);
    o4.w = (unsigned char)(tA[i][j0 + 3] + 10 * tB[j0 + 3][i]);
    *(uchar4*)(packed + base + (long)(qt * 32 + i) * SS + kt * 32 + j0) = o4;
}

// ---------------- Fused attention (flash-style, fp32) ----------------
// grid (S/32, H, B); block 256. Thread (r=tid/8 row, gg=tid%8).
// scores = (q.k)/sqrt(32) * (1 + table[packed]); online softmax; O = P@V.
__global__ __launch_bounds__(256) void attn_kernel(
    const float* __restrict__ q, const float* __restrict__ k,
    const float* __restrict__ v, const unsigned char* __restrict__ packed,
    const float* __restrict__ emb_f, const float* __restrict__ emb_b,
    float* __restrict__ o)
{
    const int qt = blockIdx.x, h = blockIdx.y, b = blockIdx.z;
    const int tid = threadIdx.x;
    const int r = tid >> 3;    // 0..31
    const int gg = tid & 7;    // 0..7
    __shared__ float table[100];
    __shared__ float Ks[64][33];
    __shared__ float Vs[64][33];
    __shared__ float Ps[32][65];
    if (tid < 100) table[tid] = emb_f[(tid % 10) * HH + h] + emb_b[(tid / 10) * HH + h];
    const int q0 = qt * 32;
    const float* qrow = q + ((long)(b * SS + q0 + r)) * DD + h * DKK;
    float qv[32];
#pragma unroll
    for (int c4 = 0; c4 < 8; c4++) {
        const float4 t4 = *(const float4*)(qrow + c4 * 4);
        qv[c4 * 4 + 0] = t4.x; qv[c4 * 4 + 1] = t4.y;
        qv[c4 * 4 + 2] = t4.z; qv[c4 * 4 + 3] = t4.w;
    }
    float mrun = -1e30f, lrun = 0.f;
    float acc0 = 0.f, acc1 = 0.f, acc2 = 0.f, acc3 = 0.f;
    const float scale = 0.17677669529663687f;  // 1/sqrt(32)
    const unsigned char* pkrow = packed + ((long)b * SS + q0 + r) * SS + gg * 8;
    for (int kt = 0; kt < SS / 64; kt++) {
        __syncthreads();
        {
            const int i = tid >> 3;
            const int j = (tid & 7) << 2;
            const float* kp = k + ((long)(b * SS + kt * 64 + i)) * DD + h * DKK + j;
            const float* vp = v + ((long)(b * SS + kt * 64 + i)) * DD + h * DKK + j;
            float4 k4 = *(const float4*)kp;
            float4 v4 = *(const float4*)vp;
            Ks[i][j + 0] = k4.x; Ks[i][j + 1] = k4.y; Ks[i][j + 2] = k4.z; Ks[i][j + 3] = k4.w;
            Vs[i][j + 0] = v4.x; Vs[i][j + 1] = v4.y; Vs[i][j + 2] = v4.z; Vs[i][j + 3] = v4.w;
            k4 = *(const float4*)(kp + 32 * DD);
            v4 = *(const float4*)(vp + 32 * DD);
            Ks[i + 32][j + 0] = k4.x; Ks[i + 32][j + 1] = k4.y; Ks[i + 32][j + 2] = k4.z; Ks[i + 32][j + 3] = k4.w;
            Vs[i + 32][j + 0] = v4.x; Vs[i + 32][j + 1] = v4.y; Vs[i + 32][j + 2] = v4.z; Vs[i + 32][j + 3] = v4.w;
        }
        __syncthreads();
        const unsigned int u0 = *(const unsigned int*)(pkrow + kt * 64);
        const unsigned int u1 = *(const unsigned int*)(pkrow + kt * 64 + 4);
        float sv[8];
#pragma unroll
        for (int p = 0; p < 8; p++) {
            const int kk = gg * 8 + p;
            float s = 0.f;
#pragma unroll
            for (int c = 0; c < 32; c++) s += qv[c] * Ks[kk][c];
            const unsigned idx = (p < 4) ? ((u0 >> (8 * p)) & 0xffu) : ((u1 >> (8 * (p - 4))) & 0xffu);
            s = s * scale * (1.f + table[idx]);
            sv[p] = s;
        }
        float mt = sv[0];
#pragma unroll
        for (int p = 1; p < 8; p++) mt = fmaxf(mt, sv[p]);
        mt = fmaxf(mt, __shfl_xor(mt, 1));
        mt = fmaxf(mt, __shfl_xor(mt, 2));
        mt = fmaxf(mt, __shfl_xor(mt, 4));
        const float mnew = fmaxf(mrun, mt);
        const float corr = __expf(mrun - mnew);
        float ts = 0.f;
#pragma unroll
        for (int p = 0; p < 8; p++) {
            const float pe = __expf(sv[p] - mnew);
            sv[p] = pe;
            ts += pe;
        }
        ts += __shfl_xor(ts, 1); ts += __shfl_xor(ts, 2); ts += __shfl_xor(ts, 4);
        lrun = lrun * corr + ts;
        mrun = mnew;
        acc0 *= corr; acc1 *= corr; acc2 *= corr; acc3 *= corr;
#pragma unroll
        for (int p = 0; p < 8; p++) Ps[r][gg * 8 + p] = sv[p];
        __syncthreads();
        for (int kk2 = 0; kk2 < 64; kk2++) {
            const float pw = Ps[r][kk2];
            acc0 += pw * Vs[kk2][gg * 4 + 0];
            acc1 += pw * Vs[kk2][gg * 4 + 1];
            acc2 += pw * Vs[kk2][gg * 4 + 2];
            acc3 += pw * Vs[kk2][gg * 4 + 3];
        }
    }
    const float invl = 1.f / lrun;
    float4 o4;
    o4.x = acc0 * invl; o4.y = acc1 * invl; o4.z = acc2 * invl; o4.w = acc3 * invl;
    *(float4*)(o + ((long)(b * SS + q0 + r)) * DD + h * DKK + gg * 4) = o4;
}

extern "C" void kernel_launch(void* const* d_in, const int* in_sizes, int n_in,
                              void* d_out, int out_size, void* d_ws, size_t ws_size,
                              hipStream_t stream)
{
    const float* x    = (const float*)d_in[0];
    const int*   rp   = (const int*)d_in[1];
    const float* adj  = (const float*)d_in[2];
    const float* ln1g = (const float*)d_in[3];
    const float* ln1b = (const float*)d_in[4];
    const float* Wk   = (const float*)d_in[5];
    const float* bk   = (const float*)d_in[6];
    const float* Wv   = (const float*)d_in[7];
    const float* bv   = (const float*)d_in[8];
    const float* Wq   = (const float*)d_in[9];
    const float* bq   = (const float*)d_in[10];
    const float* Wo   = (const float*)d_in[11];
    const float* bo   = (const float*)d_in[12];
    const float* embf = (const float*)d_in[13];
    const float* embb = (const float*)d_in[14];
    const float* ln2g = (const float*)d_in[15];
    const float* ln2b = (const float*)d_in[16];
    const float* W1   = (const float*)d_in[17];
    const float* b1   = (const float*)d_in[18];
    const float* Wg   = (const float*)d_in[19];
    const float* bg   = (const float*)d_in[20];
    const float* W2   = (const float*)d_in[21];
    const float* b2   = (const float*)d_in[22];
    float* out = (float*)d_out;

    char* ws = (char*)d_ws;
    float* xn = (float*)(ws + 0);                       // 8 MB  [B,S,D]
    float* x2 = (float*)(ws + (8ll << 20));             // 8 MB  [B,S,D]
    float* qb = (float*)(ws + (16ll << 20));            // 8 MB
    float* kb = (float*)(ws + (24ll << 20));            // 8 MB
    float* vb = (float*)(ws + (32ll << 20));            // 8 MB
    unsigned char* pk = (unsigned char*)(ws + (40ll << 20)); // 8 MB uint8
    float* ob = (float*)(ws + (48ll << 20));            // 8 MB
    // phase 2 (after attention) overlaps dead phase-1 buffers:
    float* x1h = (float*)(ws + (16ll << 20));           // 32 MB [B,S,HID]
    float* gb  = (float*)(ws + (48ll << 20));           // 32 MB [B,S,HID]

    const int rows = BQ * SS;  // 8192
    dim3 blk(256);

    // LN1
    ln_kernel<<<rows, blk, 0, stream>>>(x, ln1g, ln1b, xn);
    // q,k,v  [B,S,D]
    gemm_kernel<false, false><<<dim3(4, 128, 1), blk, 0, stream>>>(
        xn, Wq, bq, nullptr, qb, rows, DD, DD, DD, DD, DD, 0, 0, 0, 0, 0);
    gemm_kernel<false, false><<<dim3(4, 128, 1), blk, 0, stream>>>(
        xn, Wk, bk, nullptr, kb, rows, DD, DD, DD, DD, DD, 0, 0, 0, 0, 0);
    gemm_kernel<false, false><<<dim3(4, 128, 1), blk, 0, stream>>>(
        xn, Wv, bv, nullptr, vb, rows, DD, DD, DD, DD, DD, 0, 0, 0, 0, 0);
    // packed rel-pos
    pack_kernel<<<dim3(32, 32, 8), blk, 0, stream>>>(rp, pk);
    // fused attention
    attn_kernel<<<dim3(32, 8, 8), blk, 0, stream>>>(qb, kb, vb, pk, embf, embb, ob);
    // x2 = x + o@Wo + bo
    gemm_kernel<false, false><<<dim3(4, 128, 1), blk, 0, stream>>>(
        ob, Wo, bo, x, x2, rows, DD, DD, DD, DD, DD, DD, 0, 0, 0, 0);
    // LN2 (reuse xn)
    ln_kernel<<<rows, blk, 0, stream>>>(x2, ln2g, ln2b, xn);
    // x1 = xn@W1 + b1 ; g = xn@Wg + bg
    gemm_kernel<false, false><<<dim3(16, 128, 1), blk, 0, stream>>>(
        xn, W1, b1, nullptr, x1h, rows, HIDD, DD, DD, HIDD, HIDD, 0, 0, 0, 0, 0);
    gemm_kernel<false, false><<<dim3(16, 128, 1), blk, 0, stream>>>(
        xn, Wg, bg, nullptr, gb, rows, HIDD, DD, DD, HIDD, HIDD, 0, 0, 0, 0, 0);
    // h[:, :512] = relu(x1[:, :512] + adj@g1)      (batched, in-place)
    gemm_kernel<false, true><<<dim3(8, 16, 8), blk, 0, stream>>>(
        adj, gb, nullptr, x1h, x1h, SS, 512, SS, SS, HIDD, HIDD, HIDD,
        (long)SS * SS, (long)SS * HIDD, (long)SS * HIDD, (long)SS * HIDD);
    // h[:, 512:] = relu(x1[:, 512:] + adjT@g2)     (batched, in-place)
    gemm_kernel<true, true><<<dim3(8, 16, 8), blk, 0, stream>>>(
        adj, gb + 512, nullptr, x1h + 512, x1h + 512, SS, 512, SS, SS, HIDD, HIDD, HIDD,
        (long)SS * SS, (long)SS * HIDD, (long)SS * HIDD, (long)SS * HIDD);
    // out = x2 + h@W2 + b2
    gemm_kernel<false, false><<<dim3(4, 128, 1), blk, 0, stream>>>(
        x1h, W2, b2, x2, out, rows, DD, HIDD, HIDD, DD, DD, DD, 0, 0, 0, 0);
}

// Round 2
// 400.383 us; speedup vs baseline: 2.7247x; 2.7247x over previous
//
#include <hip/hip_runtime.h>
#include <hip/hip_bf16.h>

#define SS 1024
#define DD 256
#define HH 8
#define DKK 32
#define HIDD 1024
#define BB 8

typedef unsigned short ushort_t;
typedef __attribute__((ext_vector_type(8))) short bf16x8;
typedef __attribute__((ext_vector_type(4))) float f32x4;
typedef __attribute__((ext_vector_type(16))) float f32x16;

__device__ __forceinline__ ushort_t f2b(float f) {
    unsigned x = __float_as_uint(f);
    unsigned r = (x + 0x7fffu + ((x >> 16) & 1u)) >> 16;
    return (ushort_t)r;
}
__device__ __forceinline__ float b2f(ushort_t u) {
    return __uint_as_float(((unsigned)u) << 16);
}
__device__ __forceinline__ void gload16(const void* g, void* l) {
    __builtin_amdgcn_global_load_lds(
        (const __attribute__((address_space(1))) unsigned int*)g,
        (__attribute__((address_space(3))) unsigned int*)l, 16, 0, 0);
}

// ---------------- LayerNorm: one row (D=256) per block, bf16 out ----------------
__global__ __launch_bounds__(256) void ln_kernel(const float* __restrict__ in,
    const float* __restrict__ gamma, const float* __restrict__ beta,
    ushort_t* __restrict__ out)
{
    const int row = blockIdx.x;
    const int t = threadIdx.x;
    const float v = in[(long)row * DD + t];
    float s = v, s2 = v * v;
#pragma unroll
    for (int off = 1; off < 64; off <<= 1) {
        s += __shfl_xor(s, off);
        s2 += __shfl_xor(s2, off);
    }
    __shared__ float w1[4], w2[4];
    if ((t & 63) == 0) { w1[t >> 6] = s; w2[t >> 6] = s2; }
    __syncthreads();
    s = w1[0] + w1[1] + w1[2] + w1[3];
    s2 = w2[0] + w2[1] + w2[2] + w2[3];
    const float mean = s * (1.f / DD);
    const float var = s2 * (1.f / DD) - mean * mean;
    const float rs = rsqrtf(var + 1e-5f);
    out[(long)row * DD + t] = f2b((v - mean) * rs * gamma[t] + beta[t]);
}

// ---------------- Weight transpose: src [R,C] f32 -> dst [C,R] bf16 ----------------
__global__ __launch_bounds__(256) void wtrans(const float* __restrict__ src,
    ushort_t* __restrict__ dst, int R, int C)
{
    const int c0 = blockIdx.x * 32, r0 = blockIdx.y * 32;
    __shared__ float t[32][33];
    const int tid = threadIdx.x;
    const int i = tid >> 3, j0 = (tid & 7) << 2;
    const float4 v = *(const float4*)(src + (long)(r0 + i) * C + c0 + j0);
    t[i][j0 + 0] = v.x; t[i][j0 + 1] = v.y; t[i][j0 + 2] = v.z; t[i][j0 + 3] = v.w;
    __syncthreads();
    ushort4 o;
    o.x = f2b(t[j0 + 0][i]); o.y = f2b(t[j0 + 1][i]);
    o.z = f2b(t[j0 + 2][i]); o.w = f2b(t[j0 + 3][i]);
    *(ushort4*)(dst + (long)(c0 + i) * R + r0 + j0) = o;
}

// ---------------- adj f32 [B,S,S] -> adjb bf16 (same layout) + adjTb bf16 (transposed) ----
__global__ __launch_bounds__(256) void adjconv(const float* __restrict__ adj,
    ushort_t* __restrict__ adjb, ushort_t* __restrict__ adjTb)
{
    const int c0 = blockIdx.x * 32, r0 = blockIdx.y * 32;
    const long base = (long)blockIdx.z * SS * SS;
    __shared__ float t[32][33];
    const int tid = threadIdx.x;
    const int i = tid >> 3, j0 = (tid & 7) << 2;
    const float4 v = *(const float4*)(adj + base + (long)(r0 + i) * SS + c0 + j0);
    t[i][j0 + 0] = v.x; t[i][j0 + 1] = v.y; t[i][j0 + 2] = v.z; t[i][j0 + 3] = v.w;
    ushort4 oc;
    oc.x = f2b(v.x); oc.y = f2b(v.y); oc.z = f2b(v.z); oc.w = f2b(v.w);
    *(ushort4*)(adjb + base + (long)(r0 + i) * SS + c0 + j0) = oc;
    __syncthreads();
    ushort4 ot;
    ot.x = f2b(t[j0 + 0][i]); ot.y = f2b(t[j0 + 1][i]);
    ot.z = f2b(t[j0 + 2][i]); ot.w = f2b(t[j0 + 3][i]);
    *(ushort4*)(adjTb + base + (long)(c0 + i) * SS + r0 + j0) = ot;
}

// ---------------- Pack rel_pos: packed[b,q,k] = rp[b,q,k] + 10*rp[b,k,q] (uint8) ----
__global__ __launch_bounds__(256) void pack_kernel(const int* __restrict__ rp,
    unsigned char* __restrict__ packed)
{
    const int kt = blockIdx.x, qt = blockIdx.y, b = blockIdx.z;
    __shared__ int tA[32][33];
    __shared__ int tB[32][33];
    const int tid = threadIdx.x;
    const int i = tid >> 3;
    const int j0 = (tid & 7) << 2;
    const long base = (long)b * SS * SS;
    const int4 a4 = *(const int4*)(rp + base + (long)(qt * 32 + i) * SS + kt * 32 + j0);
    tA[i][j0 + 0] = a4.x; tA[i][j0 + 1] = a4.y; tA[i][j0 + 2] = a4.z; tA[i][j0 + 3] = a4.w;
    const int4 b4 = *(const int4*)(rp + base + (long)(kt * 32 + i) * SS + qt * 32 + j0);
    tB[i][j0 + 0] = b4.x; tB[i][j0 + 1] = b4.y; tB[i][j0 + 2] = b4.z; tB[i][j0 + 3] = b4.w;
    __syncthreads();
    uchar4 o4;
    o4.x = (unsigned char)(tA[i][j0 + 0] + 10 * tB[j0 + 0][i]);
    o4.y = (unsigned char)(tA[i][j0 + 1] + 10 * tB[j0 + 1][i]);
    o4.z = (unsigned char)(tA[i][j0 + 2] + 10 * tB[j0 + 2][i]);
    o4.w = (unsigned char)(tA[i][j0 + 3] + 10 * tB[j0 + 3][i]);
    *(uchar4*)(packed + base + (long)(qt * 32 + i) * SS + kt * 32 + j0) = o4;
}

// ---------------- MFMA GEMM: C = A(bf16,[M,K]) @ BT(bf16,[N,K])^T  ----------------
// 128x64 tile, BK=32, 256 threads (4 waves 2x2), per-wave 64x32 via 16x16x32 frags.
// MODE 0: f32 out (+f32 Res); MODE 1: bf16 out (+bf16 Res); MODE 2: bf16 transposed
// batched out: C[(m/tbRows)*tbStride + n*tbRows + m%tbRows].
template<int MODE, bool RELU>
__global__ __launch_bounds__(256) void mgemm(
    const ushort_t* __restrict__ A, const ushort_t* __restrict__ BT,
    const float* __restrict__ bias, const void* __restrict__ Res, void* __restrict__ C,
    int M, int N, int K, int lda, int ldbt, int ldc,
    long sA, long sBT, long sC, long sRes, long tbStride, int tbRows)
{
    const int z = blockIdx.z;
    const ushort_t* Ap = A + (long)z * sA;
    const ushort_t* Bp = BT + (long)z * sBT;
    const int n0 = blockIdx.x * 64, m0 = blockIdx.y * 128;
    const int tid = threadIdx.x, wid = tid >> 6, lane = tid & 63;
    const int wr = wid >> 1, wc = wid & 1;
    const int l4 = lane & 15, lh = lane >> 4;
    __shared__ ushort_t Asb[128 * 32];
    __shared__ ushort_t Bsb[64 * 32];
    f32x4 acc[4][2] = {};
    const int srow = lane >> 2, scg = lane & 3;
    for (int k0 = 0; k0 < K; k0 += 32) {
        gload16(Ap + (long)(m0 + wid * 16 + srow) * lda + k0 + scg * 8, &Asb[wid * 512]);
        gload16(Ap + (long)(m0 + (wid + 4) * 16 + srow) * lda + k0 + scg * 8, &Asb[(wid + 4) * 512]);
        gload16(Bp + (long)(n0 + wid * 16 + srow) * ldbt + k0 + scg * 8, &Bsb[wid * 512]);
        __syncthreads();
        bf16x8 af[4], bfr[2];
#pragma unroll
        for (int mi = 0; mi < 4; mi++)
            af[mi] = *(const bf16x8*)&Asb[(wr * 64 + mi * 16 + l4) * 32 + lh * 8];
#pragma unroll
        for (int nj = 0; nj < 2; nj++)
            bfr[nj] = *(const bf16x8*)&Bsb[(wc * 32 + nj * 16 + l4) * 32 + lh * 8];
#pragma unroll
        for (int mi = 0; mi < 4; mi++)
#pragma unroll
            for (int nj = 0; nj < 2; nj++)
                acc[mi][nj] = __builtin_amdgcn_mfma_f32_16x16x32_bf16(af[mi], bfr[nj], acc[mi][nj], 0, 0, 0);
        __syncthreads();
    }
#pragma unroll
    for (int mi = 0; mi < 4; mi++) {
#pragma unroll
        for (int nj = 0; nj < 2; nj++) {
            const int n = n0 + wc * 32 + nj * 16 + l4;
            const int mb = m0 + wr * 64 + mi * 16 + lh * 4;
            const float bv = bias ? bias[n] : 0.f;
            if (MODE == 0) {
                float* Cp = (float*)C + (long)z * sC;
                const float* Rp = Res ? (const float*)Res + (long)z * sRes : (const float*)0;
#pragma unroll
                for (int r = 0; r < 4; r++) {
                    float v = acc[mi][nj][r] + bv;
                    if (Rp) v += Rp[(long)(mb + r) * ldc + n];
                    if (RELU) v = fmaxf(v, 0.f);
                    Cp[(long)(mb + r) * ldc + n] = v;
                }
            } else if (MODE == 1) {
                ushort_t* Cp = (ushort_t*)C + (long)z * sC;
                const ushort_t* Rp = Res ? (const ushort_t*)Res + (long)z * sRes : (const ushort_t*)0;
#pragma unroll
                for (int r = 0; r < 4; r++) {
                    float v = acc[mi][nj][r] + bv;
                    if (Rp) v += b2f(Rp[(long)(mb + r) * ldc + n]);
                    if (RELU) v = fmaxf(v, 0.f);
                    Cp[(long)(mb + r) * ldc + n] = f2b(v);
                }
            } else {
                ushort_t* Cp = (ushort_t*)C;
                const int bidx = mb / tbRows;
                const int s = mb - bidx * tbRows;
                ushort4 o4;
                o4.x = f2b(acc[mi][nj][0] + bv);
                o4.y = f2b(acc[mi][nj][1] + bv);
                o4.z = f2b(acc[mi][nj][2] + bv);
                o4.w = f2b(acc[mi][nj][3] + bv);
                *(ushort4*)(Cp + (long)bidx * tbStride + (long)n * tbRows + s) = o4;
            }
        }
    }
}

// ---------------- Fused attention, swapped-operand MFMA flash ----------------
// grid (S/128, H, B), 256 thr = 4 waves, each wave one 32-row q-tile, KBLK=32.
// S^T = K@Q^T (lane owns q=lane&31, 16 k-values); softmax in-register;
// P->bf16 + shfl_xor(32) half exchange; O^T = V^T@P^T from transposed V.
__global__ __launch_bounds__(256) void attn2(
    const ushort_t* __restrict__ qb, const ushort_t* __restrict__ kb,
    const ushort_t* __restrict__ vt, const unsigned char* __restrict__ pkd,
    const float* __restrict__ ef, const float* __restrict__ eb,
    ushort_t* __restrict__ ob)
{
    const int h = blockIdx.y, b = blockIdx.z;
    const int tid = threadIdx.x;
    const int wid = tid >> 6, lane = tid & 63;
    const int l31 = lane & 31, hi = lane >> 5;
    __shared__ float tm[100];
    if (tid < 100)
        tm[tid] = 0.17677669529663687f * (1.f + ef[(tid % 10) * HH + h] + eb[(tid / 10) * HH + h]);
    __syncthreads();
    const int q0 = (blockIdx.x * 4 + wid) * 32;
    const long qoff = ((long)(b * SS + q0 + l31)) * DD + h * DKK + hi * 8;
    const bf16x8 qlo = *(const bf16x8*)(qb + qoff);
    const bf16x8 qhi = *(const bf16x8*)(qb + qoff + 16);
    const unsigned char* prow = pkd + ((long)(b * SS + q0 + l31)) * SS;
    const ushort_t* vrow = vt + ((long)(b * DD + h * DKK + l31)) * SS + hi * 8;
    f32x16 acc = {};
    float mrun = -1e30f, lrun = 0.f;
    for (int kt = 0; kt < SS; kt += 32) {
        const long koff = ((long)(b * SS + kt + l31)) * DD + h * DKK + hi * 8;
        const bf16x8 klo = *(const bf16x8*)(kb + koff);
        const bf16x8 khi = *(const bf16x8*)(kb + koff + 16);
        f32x16 sf = {};
        sf = __builtin_amdgcn_mfma_f32_32x32x16_bf16(klo, qlo, sf, 0, 0, 0);
        sf = __builtin_amdgcn_mfma_f32_32x32x16_bf16(khi, qhi, sf, 0, 0, 0);
        const uint4 u0 = *(const uint4*)(prow + kt);
        const uint4 u1 = *(const uint4*)(prow + kt + 16);
        float p[16];
        {
            const unsigned wa = hi ? u0.y : u0.x;
            const unsigned wb = hi ? u0.w : u0.z;
            const unsigned wc2 = hi ? u1.y : u1.x;
            const unsigned wd = hi ? u1.w : u1.z;
#pragma unroll
            for (int rb = 0; rb < 4; rb++) {
                p[0 + rb]  = sf[0 + rb]  * tm[(wa  >> (8 * rb)) & 255u];
                p[4 + rb]  = sf[4 + rb]  * tm[(wb  >> (8 * rb)) & 255u];
                p[8 + rb]  = sf[8 + rb]  * tm[(wc2 >> (8 * rb)) & 255u];
                p[12 + rb] = sf[12 + rb] * tm[(wd  >> (8 * rb)) & 255u];
            }
        }
        float mt = p[0];
#pragma unroll
        for (int r = 1; r < 16; r++) mt = fmaxf(mt, p[r]);
        mt = fmaxf(mt, __shfl_xor(mt, 32));
        const float mnew = fmaxf(mrun, mt);
        const float corr = __expf(mrun - mnew);
        float ts = 0.f;
#pragma unroll
        for (int r = 0; r < 16; r++) { p[r] = __expf(p[r] - mnew); ts += p[r]; }
        ts += __shfl_xor(ts, 32);
        lrun = lrun * corr + ts;
        mrun = mnew;
        acc = acc * corr;
        const unsigned c0_ = (unsigned)f2b(p[0])  | ((unsigned)f2b(p[1])  << 16);
        const unsigned c1_ = (unsigned)f2b(p[2])  | ((unsigned)f2b(p[3])  << 16);
        const unsigned c2_ = (unsigned)f2b(p[4])  | ((unsigned)f2b(p[5])  << 16);
        const unsigned c3_ = (unsigned)f2b(p[6])  | ((unsigned)f2b(p[7])  << 16);
        const unsigned c4_ = (unsigned)f2b(p[8])  | ((unsigned)f2b(p[9])  << 16);
        const unsigned c5_ = (unsigned)f2b(p[10]) | ((unsigned)f2b(p[11]) << 16);
        const unsigned c6_ = (unsigned)f2b(p[12]) | ((unsigned)f2b(p[13]) << 16);
        const unsigned c7_ = (unsigned)f2b(p[14]) | ((unsigned)f2b(p[15]) << 16);
        const unsigned d0_ = (unsigned)__shfl_xor((int)c0_, 32);
        const unsigned d1_ = (unsigned)__shfl_xor((int)c1_, 32);
        const unsigned d2_ = (unsigned)__shfl_xor((int)c2_, 32);
        const unsigned d3_ = (unsigned)__shfl_xor((int)c3_, 32);
        const unsigned d4_ = (unsigned)__shfl_xor((int)c4_, 32);
        const unsigned d5_ = (unsigned)__shfl_xor((int)c5_, 32);
        const unsigned d6_ = (unsigned)__shfl_xor((int)c6_, 32);
        const unsigned d7_ = (unsigned)__shfl_xor((int)c7_, 32);
        union { uint4 u; bf16x8 v; } f1, f2;
        f1.u = make_uint4(hi ? d2_ : c0_, hi ? d3_ : c1_, hi ? c2_ : d0_, hi ? c3_ : d1_);
        f2.u = make_uint4(hi ? d6_ : c4_, hi ? d7_ : c5_, hi ? c6_ : d4_, hi ? c7_ : d5_);
        const bf16x8 vlo = *(const bf16x8*)(vrow + kt);
        const bf16x8 vhi = *(const bf16x8*)(vrow + kt + 16);
        acc = __builtin_amdgcn_mfma_f32_32x32x16_bf16(vlo, f1.v, acc, 0, 0, 0);
        acc = __builtin_amdgcn_mfma_f32_32x32x16_bf16(vhi, f2.v, acc, 0, 0, 0);
    }
    const float invl = 1.f / lrun;
    ushort_t* orow = ob + ((long)(b * SS + q0 + l31)) * DD + h * DKK + 4 * hi;
#pragma unroll
    for (int g = 0; g < 4; g++) {
        ushort4 o4;
        o4.x = f2b(acc[4 * g + 0] * invl);
        o4.y = f2b(acc[4 * g + 1] * invl);
        o4.z = f2b(acc[4 * g + 2] * invl);
        o4.w = f2b(acc[4 * g + 3] * invl);
        *(ushort4*)(orow + 8 * g) = o4;
    }
}

extern "C" void kernel_launch(void* const* d_in, const int* in_sizes, int n_in,
                              void* d_out, int out_size, void* d_ws, size_t ws_size,
                              hipStream_t stream)
{
    const float* x    = (const float*)d_in[0];
    const int*   rp   = (const int*)d_in[1];
    const float* adj  = (const float*)d_in[2];
    const float* ln1g = (const float*)d_in[3];
    const float* ln1b = (const float*)d_in[4];
    const float* Wk   = (const float*)d_in[5];
    const float* bk   = (const float*)d_in[6];
    const float* Wv   = (const float*)d_in[7];
    const float* bv   = (const float*)d_in[8];
    const float* Wq   = (const float*)d_in[9];
    const float* bq   = (const float*)d_in[10];
    const float* Wo   = (const float*)d_in[11];
    const float* bo   = (const float*)d_in[12];
    const float* embf = (const float*)d_in[13];
    const float* embb = (const float*)d_in[14];
    const float* ln2g = (const float*)d_in[15];
    const float* ln2b = (const float*)d_in[16];
    const float* W1   = (const float*)d_in[17];
    const float* b1   = (const float*)d_in[18];
    const float* Wg   = (const float*)d_in[19];
    const float* bg   = (const float*)d_in[20];
    const float* W2   = (const float*)d_in[21];
    const float* b2   = (const float*)d_in[22];
    float* out = (float*)d_out;

    char* ws = (char*)d_ws;
    const long MB = 1ll << 20;
    // phase-1 region (0-28MB), overlaid in phase 2 by adjb/adjTb
    ushort_t* xnb  = (ushort_t*)(ws + 0);        // 4MB [B,S,D] bf16
    ushort_t* qbb  = (ushort_t*)(ws + 4 * MB);   // 4MB
    ushort_t* kbb  = (ushort_t*)(ws + 8 * MB);   // 4MB
    ushort_t* vtb  = (ushort_t*)(ws + 12 * MB);  // 4MB [B,D,S] transposed
    unsigned char* pkb = (unsigned char*)(ws + 16 * MB); // 8MB
    ushort_t* obb  = (ushort_t*)(ws + 24 * MB);  // 4MB
    ushort_t* adjb = (ushort_t*)(ws + 0);        // 16MB (phase 2 overlay)
    ushort_t* adjTb= (ushort_t*)(ws + 16 * MB);  // 16MB (phase 2 overlay)
    ushort_t* xn2b = (ushort_t*)(ws + 32 * MB);  // 4MB
    float*    x2   = (float*)(ws + 36 * MB);     // 8MB f32
    ushort_t* x1hb = (ushort_t*)(ws + 44 * MB);  // 16MB [B,S,HID] bf16 (x1, then h in-place)
    ushort_t* gtb  = (ushort_t*)(ws + 60 * MB);  // 16MB [B,HID,S] bf16 transposed
    ushort_t* wT   = (ushort_t*)(ws + 76 * MB);  // 2MB weights^T
    ushort_t* WqT = wT;
    ushort_t* WkT = wT + 65536;
    ushort_t* WvT = wT + 131072;
    ushort_t* WoT = wT + 196608;
    ushort_t* W1T = wT + 262144;
    ushort_t* WgT = wT + 524288;
    ushort_t* W2T = wT + 786432;

    const int rows = BB * SS;  // 8192
    dim3 blk(256);

    // weight transposes -> [N,K] bf16
    wtrans<<<dim3(8, 8), blk, 0, stream>>>(Wq, WqT, DD, DD);
    wtrans<<<dim3(8, 8), blk, 0, stream>>>(Wk, WkT, DD, DD);
    wtrans<<<dim3(8, 8), blk, 0, stream>>>(Wv, WvT, DD, DD);
    wtrans<<<dim3(8, 8), blk, 0, stream>>>(Wo, WoT, DD, DD);
    wtrans<<<dim3(32, 8), blk, 0, stream>>>(W1, W1T, DD, HIDD);
    wtrans<<<dim3(32, 8), blk, 0, stream>>>(Wg, WgT, DD, HIDD);
    wtrans<<<dim3(8, 32), blk, 0, stream>>>(W2, W2T, HIDD, DD);

    // LN1 -> bf16
    ln_kernel<<<rows, blk, 0, stream>>>(x, ln1g, ln1b, xnb);
    // q, k (normal bf16), v (transposed bf16 [B,D,S])
    mgemm<1, false><<<dim3(4, 64, 1), blk, 0, stream>>>(
        xnb, WqT, bq, nullptr, qbb, rows, DD, DD, DD, DD, DD, 0, 0, 0, 0, 0, 1);
    mgemm<1, false><<<dim3(4, 64, 1), blk, 0, stream>>>(
        xnb, WkT, bk, nullptr, kbb, rows, DD, DD, DD, DD, DD, 0, 0, 0, 0, 0, 1);
    mgemm<2, false><<<dim3(4, 64, 1), blk, 0, stream>>>(
        xnb, WvT, bv, nullptr, vtb, rows, DD, DD, DD, DD, 0, 0, 0, 0, 0, (long)DD * SS, SS);
    // packed rel-pos
    pack_kernel<<<dim3(32, 32, 8), blk, 0, stream>>>(rp, pkb);
    // fused attention
    attn2<<<dim3(8, 8, 8), blk, 0, stream>>>(qbb, kbb, vtb, pkb, embf, embb, obb);
    // x2 = x + o@Wo + bo (f32)
    mgemm<0, false><<<dim3(4, 64, 1), blk, 0, stream>>>(
        obb, WoT, bo, x, x2, rows, DD, DD, DD, DD, DD, 0, 0, 0, 0, 0, 1);
    // adj -> bf16 + bf16^T (overlays dead phase-1 buffers; stream-ordered after attn/Wo)
    adjconv<<<dim3(32, 32, 8), blk, 0, stream>>>(adj, adjb, adjTb);
    // LN2 -> bf16
    ln_kernel<<<rows, blk, 0, stream>>>(x2, ln2g, ln2b, xn2b);
    // x1 = xn@W1 + b1 (bf16), gt = (xn@Wg + bg)^T per batch (bf16 [B,HID,S])
    mgemm<1, false><<<dim3(16, 64, 1), blk, 0, stream>>>(
        xn2b, W1T, b1, nullptr, x1hb, rows, HIDD, DD, DD, DD, HIDD, 0, 0, 0, 0, 0, 1);
    mgemm<2, false><<<dim3(16, 64, 1), blk, 0, stream>>>(
        xn2b, WgT, bg, nullptr, gtb, rows, HIDD, DD, DD, DD, 0, 0, 0, 0, 0, (long)HIDD * SS, SS);
    // h[:, :512] = relu(x1[:, :512] + adj@g1), in-place, batched
    mgemm<1, true><<<dim3(8, 8, 8), blk, 0, stream>>>(
        adjb, gtb, nullptr, x1hb, x1hb, SS, 512, SS, SS, SS, HIDD,
        (long)SS * SS, (long)HIDD * SS, (long)SS * HIDD, (long)SS * HIDD, 0, 1);
    // h[:, 512:] = relu(x1[:, 512:] + adjT@g2), in-place, batched
    mgemm<1, true><<<dim3(8, 8, 8), blk, 0, stream>>>(
        adjTb, gtb + (long)512 * SS, nullptr, x1hb + 512, x1hb + 512, SS, 512, SS, SS, SS, HIDD,
        (long)SS * SS, (long)HIDD * SS, (long)SS * HIDD, (long)SS * HIDD, 0, 1);
    // out = x2 + h@W2 + b2 (f32)
    mgemm<0, false><<<dim3(4, 64, 1), blk, 0, stream>>>(
        x1hb, W2T, b2, x2, out, rows, DD, HIDD, HIDD, HIDD, DD, 0, 0, 0, 0, 0, 1);
}